// Round 1
// baseline (5182.819 us; speedup 1.0000x reference)
//
#include <hip/hip_runtime.h>
#include <cstdint>
#include <cstddef>

// ---------------------------------------------------------------------------
// LSTM  B=64, T=1024, D=H=512.
//   * xcvt: x_seq fp32 -> fp16 in ws (one-time).
//   * lstm_rec: persistent, 256 WGs = 8 batch-groups x 32 column-groups.
//     WG (g,c): batch rows g*8..g*8+7, hidden units c*16..c*16+15.
//     R3: self-synchronizing tagged h (tag<<16 | fp16), double-buffered;
//     whole-WG cooperative spin-load IS the data load.
//   R4 (this round):
//     * Loop-invariant B-fragments (Wh, Wx) hoisted to registers; LDS weight
//       arrays dropped (weights load global->reg in prologue). 96KB LDS pad
//       keeps the verified 1 WG/CU placement.
//     * x-prefetch for t+1 issued at TOP of iteration; raw s_barrier
//       (lgkmcnt-only wait) replaces __syncthreads so the global loads stay
//       in flight across both barriers -> post-publish tail is 16 pure-reg
//       MFMAs instead of L3-latency + MFMAs.
//     * s_sleep(2) backoff after first poll miss cuts L3 spin traffic.
// ---------------------------------------------------------------------------

typedef _Float16 half8  __attribute__((ext_vector_type(8)));
typedef float    float4v __attribute__((ext_vector_type(4)));

__device__ __forceinline__ float sigm(float x) { return 1.f / (1.f + __expf(-x)); }
__device__ __forceinline__ float tanh_f(float x) { return 2.f / (1.f + __expf(-2.f * x)) - 1.f; }

// ----------------------------- x fp32 -> fp16 ------------------------------
__global__ __launch_bounds__(256) void xcvt(const float* __restrict__ X,
                                            _Float16* __restrict__ XH) {
    size_t i = ((size_t)blockIdx.x * 256 + threadIdx.x) * 8;
    float4 a = *(const float4*)(X + i);
    float4 b = *(const float4*)(X + i + 4);
    half8 v;
    v[0] = (_Float16)a.x; v[1] = (_Float16)a.y; v[2] = (_Float16)a.z; v[3] = (_Float16)a.w;
    v[4] = (_Float16)b.x; v[5] = (_Float16)b.y; v[6] = (_Float16)b.z; v[7] = (_Float16)b.w;
    *(half8*)(XH + i) = v;
}

// ------------------------------- recurrence --------------------------------
__global__ __launch_bounds__(256, 1) void lstm_rec(
    const float* __restrict__ Whf, const float* __restrict__ Whi,
    const float* __restrict__ Whg, const float* __restrict__ Who,
    const float* __restrict__ Wxf, const float* __restrict__ Wxi,
    const float* __restrict__ Wxg, const float* __restrict__ Wxo,
    const float* __restrict__ bxf, const float* __restrict__ bxi,
    const float* __restrict__ bxg, const float* __restrict__ bxo,
    const float* __restrict__ bhf, const float* __restrict__ bhi,
    const float* __restrict__ bhg, const float* __restrict__ bho,
    const _Float16* __restrict__ XH,        // [64][1024][512] fp16
    unsigned long long* __restrict__ hws,   // tagged h [2][8][8][256] u64, zeroed
    float* __restrict__ out)                // [64][512] fp32
{
    const int blk  = blockIdx.x;
    const int g    = blk & 7;    // batch group (one XCD under round-robin)
    const int c    = blk >> 3;   // column group 0..31
    const int tid  = threadIdx.x;
    const int w    = tid >> 6;   // wave 0..3 -> gate segment f/i/g/o
    const int lane = tid & 63;
    const int l15  = lane & 15;
    const int quad = lane >> 4;
    const int m    = l15 & 7;    // batch row within group (rows 8..15 dup 0..7)

    // 96KB static LDS: forces 1 WG/CU (preserves verified placement); only
    // the head is used: hls [8][520] fp16 @0, gs [8][65] f32 @8448.
    __shared__ char smem[98304];
    _Float16 (*hls)[520] = (_Float16 (*)[520])smem;
    float    (*gs)[65]   = (float (*)[65])(smem + 8448);

    // ---- loop-invariant B-fragments: global fp32 -> fp16 regs (one-time) ----
    // wave w owns gate segment w (f/i/g/o), rows c*16+l15, k-slice quad*8+kk*32.
    const float* Whp = (w == 0) ? Whf : (w == 1) ? Whi : (w == 2) ? Whg : Who;
    const float* Wxp = (w == 0) ? Wxf : (w == 1) ? Wxi : (w == 2) ? Wxg : Wxo;
    const float* wrow = Whp + (size_t)(c * 16 + l15) * 512 + quad * 8;
    const float* xrw  = Wxp + (size_t)(c * 16 + l15) * 512 + quad * 8;
    half8 wb[16], xb[16];
#pragma unroll
    for (int kk = 0; kk < 16; kk++) {
        float4 a0 = *(const float4*)(wrow + kk * 32);
        float4 a1 = *(const float4*)(wrow + kk * 32 + 4);
        float4 b0 = *(const float4*)(xrw + kk * 32);
        float4 b1 = *(const float4*)(xrw + kk * 32 + 4);
        half8 vw = {(_Float16)a0.x, (_Float16)a0.y, (_Float16)a0.z, (_Float16)a0.w,
                    (_Float16)a1.x, (_Float16)a1.y, (_Float16)a1.z, (_Float16)a1.w};
        half8 vx = {(_Float16)b0.x, (_Float16)b0.y, (_Float16)b0.z, (_Float16)b0.w,
                    (_Float16)b1.x, (_Float16)b1.y, (_Float16)b1.z, (_Float16)b1.w};
        wb[kk] = vw;
        xb[kk] = vx;
    }

    // ---- elementwise role: wave 0 only, 64 threads x (1 row, 2 units) ----
    const int erow = tid >> 3;        // 0..7  (valid for tid<64)
    const int ep   = tid & 7;         // unit pair 0..7 -> units 2ep, 2ep+1
    float bs[8] = {0.f};              // f0,i0,g0,o0,f1,i1,g1,o1
    if (tid < 64) {
        int u0 = c * 16 + 2 * ep, u1 = u0 + 1;
        bs[0] = bxf[u0] + bhf[u0];  bs[4] = bxf[u1] + bhf[u1];
        bs[1] = bxi[u0] + bhi[u0];  bs[5] = bxi[u1] + bhi[u1];
        bs[2] = bxg[u0] + bhg[u0];  bs[6] = bxg[u1] + bhg[u1];
        bs[3] = bxo[u0] + bho[u0];  bs[7] = bxo[u1] + bho[u1];
    }
    float c0s = 0.f, c1s = 0.f;

    // consumer staging role: lane loads 8 tagged u64 (one 64B line) of group h
    const int crow = tid >> 5;          // 0..7
    const int ccol = (tid & 31) << 4;   // 0..496

    // ---- x-projection shadow: acc_x for step 0 (pure-reg MFMA) ----
    const size_t xrow = (size_t)(g * 8 + m) * 1024 * 512 + (size_t)quad * 8;
    half8 xf[16];
#pragma unroll
    for (int kk = 0; kk < 16; kk++) xf[kk] = *(const half8*)(XH + xrow + kk * 32);
    float4v accx = {0.f, 0.f, 0.f, 0.f};
#pragma unroll
    for (int kk = 0; kk < 16; kk++)
        accx = __builtin_amdgcn_mfma_f32_16x16x32_f16(xf[kk], xb[kk], accx, 0, 0, 0);

    for (int t = 0; t < 1024; t++) {
        // ---- cooperative tagged spin-load of h_t -> LDS (poll IS the load)
        {
            const unsigned long long* hsrc = hws + (size_t)(t & 1) * 16384
                                           + (size_t)g * 2048 + (size_t)tid * 8;
            const unsigned long long T =
                ((unsigned long long)(unsigned)t << 16) |
                ((unsigned long long)(unsigned)t << 48);
            unsigned long long q[8];
            int miss = 0;
            for (;;) {
                unsigned long long bad = 0;
#pragma unroll
                for (int j = 0; j < 8; j++)
                    q[j] = __hip_atomic_load(hsrc + j, __ATOMIC_RELAXED,
                                             __HIP_MEMORY_SCOPE_AGENT);
#pragma unroll
                for (int j = 0; j < 8; j++)
                    bad |= (q[j] ^ T) & 0xFFFF0000FFFF0000ULL;
                if (!bad) break;
                if (miss++) __builtin_amdgcn_s_sleep(2);  // backoff after 1st miss
            }
            unsigned int* hd = (unsigned int*)&hls[crow][ccol];
#pragma unroll
            for (int j = 0; j < 8; j++)
                hd[j] = (unsigned int)(q[j] & 0xFFFF) |
                        (((unsigned int)(q[j] >> 32)) << 16);
        }

        // ---- issue x loads for t+1 NOW; they stay in flight across the raw
        // barriers (lgkmcnt-only waits) and complete long before the tail MFMAs.
        {
            int tn = (t < 1023) ? (t + 1) : 0;
            const _Float16* xp = XH + xrow + (size_t)tn * 512;
#pragma unroll
            for (int kk = 0; kk < 16; kk++) xf[kk] = *(const half8*)(xp + kk * 32);
        }

        // barrier 1: hls staged (ds_writes drained; vmcnt NOT drained)
        asm volatile("s_waitcnt lgkmcnt(0)" ::: "memory");
        __builtin_amdgcn_s_barrier();
        __builtin_amdgcn_sched_barrier(0);

        // ---- h-GEMM: acc = acc_x + h_t @ Wh_slice^T (A from LDS, B in regs) ----
        float4v acca = accx;
        float4v accb = {0.f, 0.f, 0.f, 0.f};
#pragma unroll
        for (int kk = 0; kk < 16; kk += 2) {
            half8 a0 = *(const half8*)&hls[m][kk * 32 + quad * 8];
            half8 a1 = *(const half8*)&hls[m][(kk + 1) * 32 + quad * 8];
            acca = __builtin_amdgcn_mfma_f32_16x16x32_f16(a0, wb[kk],     acca, 0, 0, 0);
            accb = __builtin_amdgcn_mfma_f32_16x16x32_f16(a1, wb[kk + 1], accb, 0, 0, 0);
        }

        // ---- gate preacts -> LDS (rows 0..7 live in quads 0,1) ----
        if (quad < 2) {
#pragma unroll
            for (int r = 0; r < 4; r++)
                gs[quad * 4 + r][w * 16 + l15] = acca[r] + accb[r];
        }
        // barrier 2: gs ready (again lgkmcnt-only)
        asm volatile("s_waitcnt lgkmcnt(0)" ::: "memory");
        __builtin_amdgcn_s_barrier();
        __builtin_amdgcn_sched_barrier(0);

        // ---- elementwise LSTM update + tagged publish (wave 0 only) ----
        if (tid < 64) {
            float pf0 = gs[erow][2 * ep]      + bs[0];
            float pi0 = gs[erow][2 * ep + 16] + bs[1];
            float pg0 = gs[erow][2 * ep + 32] + bs[2];
            float po0 = gs[erow][2 * ep + 48] + bs[3];
            float pf1 = gs[erow][2 * ep + 1]  + bs[4];
            float pi1 = gs[erow][2 * ep + 17] + bs[5];
            float pg1 = gs[erow][2 * ep + 33] + bs[6];
            float po1 = gs[erow][2 * ep + 49] + bs[7];
            c0s = sigm(pf0) * c0s + sigm(pi0) * tanh_f(pg0);
            c1s = sigm(pf1) * c1s + sigm(pi1) * tanh_f(pg1);
            float hn0 = sigm(po0) * tanh_f(c0s);
            float hn1 = sigm(po1) * tanh_f(c1s);
            union { _Float16 f; unsigned short u; } cv0, cv1;
            cv0.f = (_Float16)hn0; cv1.f = (_Float16)hn1;
            unsigned int tag = (unsigned)(t + 1) << 16;
            unsigned long long qv = (unsigned long long)(tag | cv0.u)
                                  | ((unsigned long long)(tag | cv1.u) << 32);
            unsigned long long* hd = hws + (size_t)((t + 1) & 1) * 16384
                                   + (size_t)g * 2048 + (size_t)erow * 256
                                   + c * 8 + ep;
            __hip_atomic_store(hd, qv, __ATOMIC_RELAXED,
                               __HIP_MEMORY_SCOPE_AGENT);
            if (t == 1023) {
                size_t ob = (size_t)(g * 8 + erow) * 512 + c * 16 + 2 * ep;
                out[ob]     = hn0;
                out[ob + 1] = hn1;
            }
        }

        // ---- x-GEMM tail for t+1: pure-register (loads issued at loop top) ----
        float4v ax = {0.f, 0.f, 0.f, 0.f};
#pragma unroll
        for (int kk = 0; kk < 16; kk++)
            ax = __builtin_amdgcn_mfma_f32_16x16x32_f16(xf[kk], xb[kk], ax, 0, 0, 0);
        accx = ax;
    }
}

// ------------------------------- launcher ----------------------------------
extern "C" void kernel_launch(void* const* d_in, const int* in_sizes, int n_in,
                              void* d_out, int out_size, void* d_ws, size_t ws_size,
                              hipStream_t stream) {
    const float* X   = (const float*)d_in[0];
    const float* Whf = (const float*)d_in[1];  const float* bhf = (const float*)d_in[2];
    const float* Wxf = (const float*)d_in[3];  const float* bxf = (const float*)d_in[4];
    const float* Whi = (const float*)d_in[5];  const float* bhi = (const float*)d_in[6];
    const float* Wxi = (const float*)d_in[7];  const float* bxi = (const float*)d_in[8];
    const float* Whg = (const float*)d_in[9];  const float* bhg = (const float*)d_in[10];
    const float* Wxg = (const float*)d_in[11]; const float* bxg = (const float*)d_in[12];
    const float* Who = (const float*)d_in[13]; const float* bho = (const float*)d_in[14];
    const float* Wxo = (const float*)d_in[15]; const float* bxo = (const float*)d_in[16];

    // ws layout: [0,256KB) tagged h double buffer | [1MB,65MB) XH fp16
    if (ws_size < (size_t)68157440) return;  // need 65 MiB

    char* ws = (char*)d_ws;
    unsigned long long* hws = (unsigned long long*)ws;
    _Float16*           XH  = (_Float16*)(ws + (1 << 20));
    (void)in_sizes; (void)n_in; (void)out_size;

    hipMemsetAsync(d_ws, 0, 262144, stream);
    xcvt<<<16384, 256, 0, stream>>>(X, XH);
    lstm_rec<<<256, 256, 0, stream>>>(Whf, Whi, Whg, Who, Wxf, Wxi, Wxg, Wxo,
                                      bxf, bxi, bxg, bxo, bhf, bhi, bhg, bho,
                                      XH, hws, (float*)d_out);
}